// Round 1
// baseline (2073.824 us; speedup 1.0000x reference)
//
#include <hip/hip_runtime.h>
#include <hip/hip_bf16.h>
#include <stdint.h>

#define HFR 128
#define HTO 128

// ---------------------------------------------------------------------------
// Kernel 1: zero the output accumulator (harness poisons d_out to 0xAA).
// ---------------------------------------------------------------------------
__global__ __launch_bounds__(256) void zero_f32x4(float4* __restrict__ p, int n4) {
    int i = blockIdx.x * 256 + threadIdx.x;
    if (i < n4) p[i] = make_float4(0.f, 0.f, 0.f, 0.f);
}

// ---------------------------------------------------------------------------
// Kernel 2: H[r][n][i] = sum_j W[r][i][j] * nodes[n][j], stored bf16.
// Block = 256 threads handles a 64-node tile for ALL R relations.
// LDS: node tile (64x128, padded stride 132) + W[r] (128x128, stride 132).
// Thread (i_grp = t&15, n_grp = t>>4) computes 4 nodes x 8 outputs.
//   outputs i = i_grp + 16*j  (consecutive lanes -> consecutive i, 2-way-max
//   bank aliasing on the padded stride-132 layout, which is free on CDNA4)
// ---------------------------------------------------------------------------
__global__ __launch_bounds__(256)
void transform_kernel(const float* __restrict__ nodes,
                      const float* __restrict__ weights,
                      __hip_bfloat16* __restrict__ H,
                      int N, int R) {
    __shared__ float nd[64 * 132];
    __shared__ float wt[128 * 132];

    const int t  = threadIdx.x;
    const int n0 = blockIdx.x * 64;

    // ---- stage node tile: 64 rows x 32 float4 = 2048 float4, 8 per thread
    for (int it = 0; it < 8; ++it) {
        int id  = t + 256 * it;        // 0..2047
        int row = id >> 5;             // 32 float4 per row
        int k4  = id & 31;
        float4 v = make_float4(0.f, 0.f, 0.f, 0.f);
        if (n0 + row < N)
            v = reinterpret_cast<const float4*>(nodes)[(size_t)(n0 + row) * 32 + k4];
        *reinterpret_cast<float4*>(&nd[row * 132 + k4 * 4]) = v;
    }

    const int i_grp = t & 15;
    const int n_grp = t >> 4;
    const int nbase = n_grp * 4;

    for (int r = 0; r < R; ++r) {
        __syncthreads();   // protect wt from previous iteration's readers
        // ---- stage W[r]: 128 rows x 32 float4 = 4096 float4, 16 per thread
        const float4* wsrc = reinterpret_cast<const float4*>(weights + (size_t)r * HFR * HTO);
        for (int it = 0; it < 16; ++it) {
            int id  = t + 256 * it;    // 0..4095
            int row = id >> 5;
            int k4  = id & 31;
            *reinterpret_cast<float4*>(&wt[row * 132 + k4 * 4]) = wsrc[row * 32 + k4];
        }
        __syncthreads();

        float acc[4][8];
#pragma unroll
        for (int m = 0; m < 4; ++m)
#pragma unroll
            for (int j = 0; j < 8; ++j) acc[m][j] = 0.f;

        for (int k = 0; k < HFR; k += 4) {
            float4 a[4];
#pragma unroll
            for (int m = 0; m < 4; ++m)
                a[m] = *reinterpret_cast<const float4*>(&nd[(nbase + m) * 132 + k]);
#pragma unroll
            for (int j = 0; j < 8; ++j) {
                int i = i_grp + 16 * j;
                float4 b = *reinterpret_cast<const float4*>(&wt[i * 132 + k]);
#pragma unroll
                for (int m = 0; m < 4; ++m) {
                    acc[m][j] += a[m].x * b.x + a[m].y * b.y
                               + a[m].z * b.z + a[m].w * b.w;
                }
            }
        }

        // ---- write H[r][n][i] as bf16 (lanes write consecutive i: coalesced)
#pragma unroll
        for (int m = 0; m < 4; ++m) {
            int n = n0 + nbase + m;
            if (n < N) {
                __hip_bfloat16* dst = H + ((size_t)r * N + n) * HTO;
#pragma unroll
                for (int j = 0; j < 8; ++j)
                    dst[i_grp + 16 * j] = __float2bfloat16(acc[m][j]);
            }
        }
    }
}

// ---------------------------------------------------------------------------
// Kernel 3: per edge e: out[dst] += v_e * H[r_e][col_e]
// One 64-lane wave per edge; lane l handles features {2l, 2l+1}.
// H read: 256B contiguous per edge (coalesced). Scatter via fp32 atomics
// into the 51.2 MB out buffer (L2/L3 resident).
// ---------------------------------------------------------------------------
__global__ __launch_bounds__(256)
void scatter_kernel(const int* __restrict__ rows,
                    const int* __restrict__ cols,
                    const float* __restrict__ vals,
                    const __hip_bfloat16* __restrict__ H,
                    float* __restrict__ out,
                    int N, long long nnz) {
    long long gidx = (long long)blockIdx.x * 256 + threadIdx.x;
    long long e = gidx >> 6;
    if (e >= nnz) return;
    int l = (int)(gidx & 63);

    int   row = rows[e];          // wave-uniform (all 64 lanes share e)
    int   col = cols[e];
    float v   = vals[e];
    int   r   = row / N;
    int   dst = row - r * N;

    const uint32_t* hp =
        reinterpret_cast<const uint32_t*>(H + ((size_t)r * N + col) * HTO);
    uint32_t pk = hp[l];                       // 2 bf16 per lane
    __hip_bfloat162 h2 = *reinterpret_cast<__hip_bfloat162*>(&pk);
    float y0 = __bfloat162float(h2.x) * v;
    float y1 = __bfloat162float(h2.y) * v;

    float* op = out + (size_t)dst * HTO + l * 2;
    atomicAdd(op,     y0);
    atomicAdd(op + 1, y1);
}

// ---------------------------------------------------------------------------
// Kernel 4: in-place relu on out.
// ---------------------------------------------------------------------------
__global__ __launch_bounds__(256) void relu_f32x4(float4* __restrict__ p, int n4) {
    int i = blockIdx.x * 256 + threadIdx.x;
    if (i < n4) {
        float4 v = p[i];
        v.x = fmaxf(v.x, 0.f); v.y = fmaxf(v.y, 0.f);
        v.z = fmaxf(v.z, 0.f); v.w = fmaxf(v.w, 0.f);
        p[i] = v;
    }
}

// ---------------------------------------------------------------------------
extern "C" void kernel_launch(void* const* d_in, const int* in_sizes, int n_in,
                              void* d_out, int out_size, void* d_ws, size_t ws_size,
                              hipStream_t stream) {
    const float* nodes   = (const float*)d_in[0];   // [N, HFR] fp32
    const int*   indices = (const int*)d_in[1];     // [2, NNZ] int32
    const float* vals    = (const float*)d_in[2];   // [NNZ] fp32
    const float* weights = (const float*)d_in[3];   // [R, HFR, HTO] fp32

    const int       N   = in_sizes[0] / HFR;
    const long long nnz = (long long)in_sizes[1] / 2;
    const int       R   = in_sizes[3] / (HFR * HTO);

    const int* rows = indices;
    const int* cols = indices + nnz;

    // Workspace: H = [R, N, HTO] bf16 (204.8 MB for the given sizes)
    __hip_bfloat16* H = (__hip_bfloat16*)d_ws;
    float* out = (float*)d_out;

    // 1) zero out accumulator
    {
        int n4 = out_size / 4;
        zero_f32x4<<<(n4 + 255) / 256, 256, 0, stream>>>((float4*)out, n4);
    }
    // 2) H[r] = nodes @ W[r]^T  (bf16 store)
    {
        int grid = (N + 63) / 64;
        transform_kernel<<<grid, 256, 0, stream>>>(nodes, weights, H, N, R);
    }
    // 3) edge gather + atomic scatter
    {
        long long work = nnz * 64;
        int grid = (int)((work + 255) / 256);
        scatter_kernel<<<grid, 256, 0, stream>>>(rows, cols, vals, H, out, N, nnz);
    }
    // 4) relu
    {
        int n4 = out_size / 4;
        relu_f32x4<<<(n4 + 255) / 256, 256, 0, stream>>>((float4*)out, n4);
    }
}

// Round 2
// 1227.328 us; speedup vs baseline: 1.6897x; 1.6897x over previous
//
#include <hip/hip_runtime.h>
#include <hip/hip_bf16.h>
#include <stdint.h>

#define HFR 128
#define HTO 128

// ---------------------------------------------------------------------------
// Kernel: zero an int array (harness poisons d_ws with 0xAA).
// ---------------------------------------------------------------------------
__global__ __launch_bounds__(256) void zero_i32(int* __restrict__ p, int n) {
    int i = blockIdx.x * 256 + threadIdx.x;
    if (i < n) p[i] = 0;
}

// ---------------------------------------------------------------------------
// Kernel: H[r][n][i] = sum_j W[r][i][j] * nodes[n][j], stored bf16.
// (unchanged from round 1 — known good; MFMA rewrite is a later round)
// ---------------------------------------------------------------------------
__global__ __launch_bounds__(256)
void transform_kernel(const float* __restrict__ nodes,
                      const float* __restrict__ weights,
                      __hip_bfloat16* __restrict__ H,
                      int N, int R) {
    __shared__ float nd[64 * 132];
    __shared__ float wt[128 * 132];

    const int t  = threadIdx.x;
    const int n0 = blockIdx.x * 64;

    for (int it = 0; it < 8; ++it) {
        int id  = t + 256 * it;
        int row = id >> 5;
        int k4  = id & 31;
        float4 v = make_float4(0.f, 0.f, 0.f, 0.f);
        if (n0 + row < N)
            v = reinterpret_cast<const float4*>(nodes)[(size_t)(n0 + row) * 32 + k4];
        *reinterpret_cast<float4*>(&nd[row * 132 + k4 * 4]) = v;
    }

    const int i_grp = t & 15;
    const int n_grp = t >> 4;
    const int nbase = n_grp * 4;

    for (int r = 0; r < R; ++r) {
        __syncthreads();
        const float4* wsrc = reinterpret_cast<const float4*>(weights + (size_t)r * HFR * HTO);
        for (int it = 0; it < 16; ++it) {
            int id  = t + 256 * it;
            int row = id >> 5;
            int k4  = id & 31;
            *reinterpret_cast<float4*>(&wt[row * 132 + k4 * 4]) = wsrc[row * 32 + k4];
        }
        __syncthreads();

        float acc[4][8];
#pragma unroll
        for (int m = 0; m < 4; ++m)
#pragma unroll
            for (int j = 0; j < 8; ++j) acc[m][j] = 0.f;

        for (int k = 0; k < HFR; k += 4) {
            float4 a[4];
#pragma unroll
            for (int m = 0; m < 4; ++m)
                a[m] = *reinterpret_cast<const float4*>(&nd[(nbase + m) * 132 + k]);
#pragma unroll
            for (int j = 0; j < 8; ++j) {
                int i = i_grp + 16 * j;
                float4 b = *reinterpret_cast<const float4*>(&wt[i * 132 + k]);
#pragma unroll
                for (int m = 0; m < 4; ++m) {
                    acc[m][j] += a[m].x * b.x + a[m].y * b.y
                               + a[m].z * b.z + a[m].w * b.w;
                }
            }
        }

#pragma unroll
        for (int m = 0; m < 4; ++m) {
            int n = n0 + nbase + m;
            if (n < N) {
                __hip_bfloat16* dst = H + ((size_t)r * N + n) * HTO;
#pragma unroll
                for (int j = 0; j < 8; ++j)
                    dst[i_grp + 16 * j] = __float2bfloat16(acc[m][j]);
            }
        }
    }
}

// ---------------------------------------------------------------------------
// Kernel: histogram of destination nodes. cnt[dst]++ per edge.
// ---------------------------------------------------------------------------
__global__ __launch_bounds__(256)
void count_kernel(const int* __restrict__ rows, int* __restrict__ cnt,
                  int N, int nnz) {
    int e = blockIdx.x * 256 + threadIdx.x;
    if (e >= nnz) return;
    int row = rows[e];
    int r   = row / N;
    int dst = row - r * N;
    atomicAdd(&cnt[dst], 1);
}

// ---------------------------------------------------------------------------
// Kernel: single-block in-place exclusive scan of cnt[0..N) -> cursor.
// 1024 threads; each owns a contiguous chunk (serial), block-scan of totals.
// ---------------------------------------------------------------------------
__global__ __launch_bounds__(1024)
void scan_kernel(int* __restrict__ cnt, int N) {
    __shared__ int sums[1024];
    const int t = threadIdx.x;
    const int chunk = (N + 1023) / 1024;
    const int lo = t * chunk;
    const int hi = min(lo + chunk, N);

    int s = 0;
    for (int i = lo; i < hi; ++i) s += cnt[i];
    sums[t] = s;
    __syncthreads();

    // Hillis-Steele inclusive scan of the 1024 per-thread totals
    for (int off = 1; off < 1024; off <<= 1) {
        int o = (t >= off) ? sums[t - off] : 0;
        __syncthreads();
        sums[t] += o;
        __syncthreads();
    }
    int running = (t == 0) ? 0 : sums[t - 1];  // exclusive prefix for my chunk

    // in-place: read old count, write exclusive prefix
    for (int i = lo; i < hi; ++i) {
        int c = cnt[i];
        cnt[i] = running;
        running += c;
    }
}

// ---------------------------------------------------------------------------
// Kernel: place each edge into its dst segment.
// pos = atomicAdd(cursor[dst], 1). Post-pass: cursor[n] == end[n] == start[n+1].
// Record packs (v | r | col) into 8 bytes.
// ---------------------------------------------------------------------------
__global__ __launch_bounds__(256)
void place_kernel(const int* __restrict__ rows, const int* __restrict__ cols,
                  const float* __restrict__ vals,
                  int* __restrict__ cursor,
                  unsigned long long* __restrict__ sorted,
                  int N, int nnz) {
    int e = blockIdx.x * 256 + threadIdx.x;
    if (e >= nnz) return;
    int row = rows[e];
    int r   = row / N;
    int dst = row - r * N;
    int pos = atomicAdd(&cursor[dst], 1);
    unsigned int lo = (unsigned int)cols[e] | ((unsigned int)r << 17);  // col < 2^17, r < 8
    unsigned long long rec =
        ((unsigned long long)__float_as_uint(vals[e]) << 32) | (unsigned long long)lo;
    sorted[pos] = rec;
}

// ---------------------------------------------------------------------------
// Kernel: pull-gather. One 64-lane wave per dst node; lane l owns features
// {2l, 2l+1}. For each edge in the node's segment: 256B coalesced read of
// H[r][col], fp32 accumulate. Single relu'd write of out[n] — no atomics.
// ---------------------------------------------------------------------------
__global__ __launch_bounds__(256)
void gather_kernel(const unsigned long long* __restrict__ sorted,
                   const int* __restrict__ cursor,
                   const __hip_bfloat16* __restrict__ H,
                   float* __restrict__ out, int N) {
    const int wave = threadIdx.x >> 6;
    const int lane = threadIdx.x & 63;
    const int n = blockIdx.x * 4 + wave;
    if (n >= N) return;

    const int start = (n == 0) ? 0 : cursor[n - 1];
    const int end   = cursor[n];

    float a0 = 0.f, a1 = 0.f;
    for (int e = start; e < end; ++e) {
        unsigned long long rec = sorted[e];              // wave-uniform address
        unsigned int lo = (unsigned int)rec;
        float v   = __uint_as_float((unsigned int)(rec >> 32));
        int   col = (int)(lo & 0x1FFFF);
        int   r   = (int)((lo >> 17) & 7);
        const unsigned int* hp =
            reinterpret_cast<const unsigned int*>(H + ((size_t)r * N + col) * HTO);
        unsigned int pk = hp[lane];                      // 2 bf16, coalesced 256B/wave
        __hip_bfloat162 h2 = *reinterpret_cast<__hip_bfloat162*>(&pk);
        a0 = fmaf(__bfloat162float(h2.x), v, a0);
        a1 = fmaf(__bfloat162float(h2.y), v, a1);
    }

    float2 o;
    o.x = fmaxf(a0, 0.f);
    o.y = fmaxf(a1, 0.f);
    *reinterpret_cast<float2*>(out + (size_t)n * HTO + lane * 2) = o;
}

// ---------------------------------------------------------------------------
extern "C" void kernel_launch(void* const* d_in, const int* in_sizes, int n_in,
                              void* d_out, int out_size, void* d_ws, size_t ws_size,
                              hipStream_t stream) {
    const float* nodes   = (const float*)d_in[0];   // [N, HFR] fp32
    const int*   indices = (const int*)d_in[1];     // [2, NNZ] int32
    const float* vals    = (const float*)d_in[2];   // [NNZ] fp32
    const float* weights = (const float*)d_in[3];   // [R, HFR, HTO] fp32

    const int N   = in_sizes[0] / HFR;
    const int nnz = in_sizes[1] / 2;
    const int R   = in_sizes[3] / (HFR * HTO);

    const int* rows = indices;
    const int* cols = indices + nnz;

    // Workspace layout:
    //   H      : [R, N, HTO] bf16   (204.8 MB)
    //   sorted : [nnz] u64          (12.8 MB)
    //   cursor : [N] int            (0.4 MB)
    char* ws = (char*)d_ws;
    __hip_bfloat16* H = (__hip_bfloat16*)ws;
    size_t H_bytes = (size_t)R * N * HTO * sizeof(__hip_bfloat16);
    unsigned long long* sorted = (unsigned long long*)(ws + H_bytes);
    int* cursor = (int*)(ws + H_bytes + (size_t)nnz * sizeof(unsigned long long));

    float* out = (float*)d_out;

    // 1) zero the histogram
    zero_i32<<<(N + 255) / 256, 256, 0, stream>>>(cursor, N);
    // 2) H[r] = nodes @ W[r]^T  (bf16 store)
    transform_kernel<<<(N + 63) / 64, 256, 0, stream>>>(nodes, weights, H, N, R);
    // 3) histogram of dst nodes
    count_kernel<<<(nnz + 255) / 256, 256, 0, stream>>>(rows, cursor, N, nnz);
    // 4) exclusive scan (in place)
    scan_kernel<<<1, 1024, 0, stream>>>(cursor, N);
    // 5) bin edges by dst
    place_kernel<<<(nnz + 255) / 256, 256, 0, stream>>>(rows, cols, vals, cursor,
                                                        sorted, N, nnz);
    // 6) pull-gather + relu (writes every out[n] exactly once)
    gather_kernel<<<(N + 3) / 4, 256, 0, stream>>>(sorted, cursor, H, out, N);
}

// Round 3
// 682.050 us; speedup vs baseline: 3.0406x; 1.7995x over previous
//
#include <hip/hip_runtime.h>
#include <hip/hip_bf16.h>
#include <stdint.h>

#define HFR 128
#define HTO 128

typedef short short8 __attribute__((ext_vector_type(8)));   // 8 bf16 = 4 VGPRs
typedef float f32x4  __attribute__((ext_vector_type(4)));   // MFMA C/D

static __device__ __forceinline__ unsigned short f2bf(float x) {
    __hip_bfloat16 h = __float2bfloat16(x);
    return *reinterpret_cast<unsigned short*>(&h);
}

// ---------------------------------------------------------------------------
// Kernel: zero an int array (harness poisons d_ws with 0xAA).
// ---------------------------------------------------------------------------
__global__ __launch_bounds__(256) void zero_i32(int* __restrict__ p, int n) {
    int i = blockIdx.x * 256 + threadIdx.x;
    if (i < n) p[i] = 0;
}

// ---------------------------------------------------------------------------
// Kernel: H[r][n][i] = sum_j W[r][i][j] * nodes[n][j], stored bf16.
// MFMA version: 128-node tile per 256-thread block (4 waves x 32 nodes).
// nodes & W[r] staged in LDS as bf16, stride 136 (pad 8 keeps 16B align,
// 2-way-max bank aliasing = free on CDNA4).
// Per wave, per K-step (K=32): 2 A-frag ds_read_b128 + 8 B-frag reads,
// 16x mfma_f32_16x16x32_bf16. C/D: col = lane&15, row = quad*4 + reg.
// ---------------------------------------------------------------------------
#define LDN 136
__global__ __launch_bounds__(256, 2)
void transform_kernel(const float* __restrict__ nodes,
                      const float* __restrict__ weights,
                      __hip_bfloat16* __restrict__ H,
                      int N, int R) {
    __shared__ unsigned short nd[128 * LDN];
    __shared__ unsigned short wt[128 * LDN];

    const int t    = threadIdx.x;
    const int n0   = blockIdx.x * 128;
    const int lane = t & 63;
    const int w    = t >> 6;        // wave id 0..3
    const int m    = lane & 15;
    const int quad = lane >> 4;     // 0..3
    const int q8   = quad * 8;
    const int w32  = w * 32;

    // ---- stage node tile: 128 rows x 128 cols fp32 -> bf16. 8 bf16/thread/it.
    const float4* src4 = reinterpret_cast<const float4*>(nodes);
#pragma unroll
    for (int it = 0; it < 8; ++it) {
        int id  = t + 256 * it;        // 0..2047
        int row = id >> 4;             // 16 x (8 bf16) per row
        int k8  = id & 15;
        float4 v0 = make_float4(0.f, 0.f, 0.f, 0.f);
        float4 v1 = v0;
        if (n0 + row < N) {
            v0 = src4[(size_t)(n0 + row) * 32 + k8 * 2];
            v1 = src4[(size_t)(n0 + row) * 32 + k8 * 2 + 1];
        }
        short8 sv;
        sv[0] = f2bf(v0.x); sv[1] = f2bf(v0.y); sv[2] = f2bf(v0.z); sv[3] = f2bf(v0.w);
        sv[4] = f2bf(v1.x); sv[5] = f2bf(v1.y); sv[6] = f2bf(v1.z); sv[7] = f2bf(v1.w);
        *reinterpret_cast<short8*>(&nd[row * LDN + k8 * 8]) = sv;
    }

    for (int r = 0; r < R; ++r) {
        __syncthreads();   // wt readers from previous r done
        // ---- stage W[r]: 128x128 fp32 -> bf16
        const float4* wsrc = reinterpret_cast<const float4*>(weights + (size_t)r * HFR * HTO);
#pragma unroll
        for (int it = 0; it < 8; ++it) {
            int id  = t + 256 * it;
            int row = id >> 4;
            int k8  = id & 15;
            float4 v0 = wsrc[row * 32 + k8 * 2];
            float4 v1 = wsrc[row * 32 + k8 * 2 + 1];
            short8 sv;
            sv[0] = f2bf(v0.x); sv[1] = f2bf(v0.y); sv[2] = f2bf(v0.z); sv[3] = f2bf(v0.w);
            sv[4] = f2bf(v1.x); sv[5] = f2bf(v1.y); sv[6] = f2bf(v1.z); sv[7] = f2bf(v1.w);
            *reinterpret_cast<short8*>(&wt[row * LDN + k8 * 8]) = sv;
        }
        __syncthreads();

        f32x4 acc[2][8];
#pragma unroll
        for (int t2 = 0; t2 < 2; ++t2)
#pragma unroll
            for (int j = 0; j < 8; ++j) acc[t2][j] = (f32x4)(0.f);

#pragma unroll
        for (int kk = 0; kk < HFR; kk += 32) {
            short8 a0 = *reinterpret_cast<const short8*>(&nd[(w32 +      m) * LDN + kk + q8]);
            short8 a1 = *reinterpret_cast<const short8*>(&nd[(w32 + 16 + m) * LDN + kk + q8]);
#pragma unroll
            for (int j = 0; j < 8; ++j) {
                short8 b = *reinterpret_cast<const short8*>(&wt[(j * 16 + m) * LDN + kk + q8]);
                acc[0][j] = __builtin_amdgcn_mfma_f32_16x16x32_bf16(a0, b, acc[0][j], 0, 0, 0);
                acc[1][j] = __builtin_amdgcn_mfma_f32_16x16x32_bf16(a1, b, acc[1][j], 0, 0, 0);
            }
        }

        // ---- write H[r]: lane writes col m + j*16 at rows quad*4+reg
#pragma unroll
        for (int t2 = 0; t2 < 2; ++t2) {
            int rowbase = n0 + w32 + t2 * 16 + quad * 4;
#pragma unroll
            for (int reg = 0; reg < 4; ++reg) {
                int n = rowbase + reg;
                if (n < N) {
                    __hip_bfloat16* dst = H + ((size_t)r * N + n) * HTO + m;
#pragma unroll
                    for (int j = 0; j < 8; ++j)
                        dst[j * 16] = __float2bfloat16(acc[t2][j][reg]);
                }
            }
        }
    }
}

// ---------------------------------------------------------------------------
// Kernel: histogram of destination nodes. cnt[dst]++ per edge.
// ---------------------------------------------------------------------------
__global__ __launch_bounds__(256)
void count_kernel(const int* __restrict__ rows, int* __restrict__ cnt,
                  int N, int nnz) {
    int e = blockIdx.x * 256 + threadIdx.x;
    if (e >= nnz) return;
    int row = rows[e];
    int r   = row / N;
    int dst = row - r * N;
    atomicAdd(&cnt[dst], 1);
}

// ---------------------------------------------------------------------------
// Kernel: single-block in-place exclusive scan of cnt[0..N) -> cursor.
// ---------------------------------------------------------------------------
__global__ __launch_bounds__(1024)
void scan_kernel(int* __restrict__ cnt, int N) {
    __shared__ int sums[1024];
    const int t = threadIdx.x;
    const int chunk = (N + 1023) / 1024;
    const int lo = t * chunk;
    const int hi = min(lo + chunk, N);

    int s = 0;
    for (int i = lo; i < hi; ++i) s += cnt[i];
    sums[t] = s;
    __syncthreads();

    for (int off = 1; off < 1024; off <<= 1) {
        int o = (t >= off) ? sums[t - off] : 0;
        __syncthreads();
        sums[t] += o;
        __syncthreads();
    }
    int running = (t == 0) ? 0 : sums[t - 1];

    for (int i = lo; i < hi; ++i) {
        int c = cnt[i];
        cnt[i] = running;
        running += c;
    }
}

// ---------------------------------------------------------------------------
// Kernel: place each edge into its dst segment (counting sort pass 2).
// ---------------------------------------------------------------------------
__global__ __launch_bounds__(256)
void place_kernel(const int* __restrict__ rows, const int* __restrict__ cols,
                  const float* __restrict__ vals,
                  int* __restrict__ cursor,
                  unsigned long long* __restrict__ sorted,
                  int N, int nnz) {
    int e = blockIdx.x * 256 + threadIdx.x;
    if (e >= nnz) return;
    int row = rows[e];
    int r   = row / N;
    int dst = row - r * N;
    int pos = atomicAdd(&cursor[dst], 1);
    unsigned int lo = (unsigned int)cols[e] | ((unsigned int)r << 17);  // col < 2^17, r < 8
    unsigned long long rec =
        ((unsigned long long)__float_as_uint(vals[e]) << 32) | (unsigned long long)lo;
    sorted[pos] = rec;
}

// ---------------------------------------------------------------------------
// Kernel: pull-gather. One 64-lane wave per dst node; lane l owns features
// {2l, 2l+1}. 256B coalesced H row read per edge, fp32 accumulate, single
// relu'd write. No atomics.
// ---------------------------------------------------------------------------
__global__ __launch_bounds__(256)
void gather_kernel(const unsigned long long* __restrict__ sorted,
                   const int* __restrict__ cursor,
                   const __hip_bfloat16* __restrict__ H,
                   float* __restrict__ out, int N) {
    const int wave = threadIdx.x >> 6;
    const int lane = threadIdx.x & 63;
    const int n = blockIdx.x * 4 + wave;
    if (n >= N) return;

    const int start = (n == 0) ? 0 : cursor[n - 1];
    const int end   = cursor[n];

    float a0 = 0.f, a1 = 0.f;
    for (int e = start; e < end; ++e) {
        unsigned long long rec = sorted[e];              // wave-uniform address
        unsigned int lo = (unsigned int)rec;
        float v   = __uint_as_float((unsigned int)(rec >> 32));
        int   col = (int)(lo & 0x1FFFF);
        int   r   = (int)((lo >> 17) & 7);
        const unsigned int* hp =
            reinterpret_cast<const unsigned int*>(H + ((size_t)r * N + col) * HTO);
        unsigned int pk = hp[lane];
        __hip_bfloat162 h2 = *reinterpret_cast<__hip_bfloat162*>(&pk);
        a0 = fmaf(__bfloat162float(h2.x), v, a0);
        a1 = fmaf(__bfloat162float(h2.y), v, a1);
    }

    float2 o;
    o.x = fmaxf(a0, 0.f);
    o.y = fmaxf(a1, 0.f);
    *reinterpret_cast<float2*>(out + (size_t)n * HTO + lane * 2) = o;
}

// ---------------------------------------------------------------------------
extern "C" void kernel_launch(void* const* d_in, const int* in_sizes, int n_in,
                              void* d_out, int out_size, void* d_ws, size_t ws_size,
                              hipStream_t stream) {
    const float* nodes   = (const float*)d_in[0];   // [N, HFR] fp32
    const int*   indices = (const int*)d_in[1];     // [2, NNZ] int32
    const float* vals    = (const float*)d_in[2];   // [NNZ] fp32
    const float* weights = (const float*)d_in[3];   // [R, HFR, HTO] fp32

    const int N   = in_sizes[0] / HFR;
    const int nnz = in_sizes[1] / 2;
    const int R   = in_sizes[3] / (HFR * HTO);

    const int* rows = indices;
    const int* cols = indices + nnz;

    // Workspace layout:
    //   H      : [R, N, HTO] bf16   (204.8 MB)
    //   sorted : [nnz] u64          (12.8 MB)
    //   cursor : [N] int            (0.4 MB)
    char* ws = (char*)d_ws;
    __hip_bfloat16* H = (__hip_bfloat16*)ws;
    size_t H_bytes = (size_t)R * N * HTO * sizeof(__hip_bfloat16);
    unsigned long long* sorted = (unsigned long long*)(ws + H_bytes);
    int* cursor = (int*)(ws + H_bytes + (size_t)nnz * sizeof(unsigned long long));

    float* out = (float*)d_out;

    // 1) zero the histogram
    zero_i32<<<(N + 255) / 256, 256, 0, stream>>>(cursor, N);
    // 2) H[r] = nodes @ W[r]^T  (bf16 MFMA, bf16 store)
    transform_kernel<<<(N + 127) / 128, 256, 0, stream>>>(nodes, weights, H, N, R);
    // 3) histogram of dst nodes
    count_kernel<<<(nnz + 255) / 256, 256, 0, stream>>>(rows, cursor, N, nnz);
    // 4) exclusive scan (in place)
    scan_kernel<<<1, 1024, 0, stream>>>(cursor, N);
    // 5) bin edges by dst
    place_kernel<<<(nnz + 255) / 256, 256, 0, stream>>>(rows, cols, vals, cursor,
                                                        sorted, N, nnz);
    // 6) pull-gather + relu (writes every out[n] exactly once)
    gather_kernel<<<(N + 3) / 4, 256, 0, stream>>>(sorted, cursor, H, out, N);
}

// Round 4
// 381.061 us; speedup vs baseline: 5.4422x; 1.7899x over previous
//
#include <hip/hip_runtime.h>
#include <hip/hip_bf16.h>
#include <stdint.h>

#define HFR 128
#define HTO 128
#define LDN 136

typedef short short8 __attribute__((ext_vector_type(8)));   // 8 bf16 = 4 VGPRs
typedef float f32x4  __attribute__((ext_vector_type(4)));   // MFMA C/D
typedef unsigned long long u64;

static __device__ __forceinline__ unsigned short f2bf(float x) {
    __hip_bfloat16 h = __float2bfloat16(x);
    return *reinterpret_cast<unsigned short*>(&h);
}
static __device__ __forceinline__ float bflo(unsigned int x) {
    return __uint_as_float(x << 16);           // low bf16 -> f32
}
static __device__ __forceinline__ float bfhi(unsigned int x) {
    return __uint_as_float(x & 0xffff0000u);   // high bf16 -> f32
}

// ---------------------------------------------------------------------------
// zero the degree histogram
// ---------------------------------------------------------------------------
__global__ __launch_bounds__(256) void zero_i32(int* __restrict__ p, int n) {
    int i = blockIdx.x * 256 + threadIdx.x;
    if (i < n) p[i] = 0;
}

// ---------------------------------------------------------------------------
// histogram of destination nodes
// ---------------------------------------------------------------------------
__global__ __launch_bounds__(256)
void count_kernel(const int* __restrict__ rows, int* __restrict__ cnt,
                  int N, int nnz) {
    int e = blockIdx.x * 256 + threadIdx.x;
    if (e >= nnz) return;
    int row = rows[e];
    int r   = row / N;
    int dst = row - r * N;
    atomicAdd(&cnt[dst], 1);
}

// ---------------------------------------------------------------------------
// hierarchical exclusive scan of cnt[0..N), coalesced.
//   scan_reduce: per-256-block sums -> bsum[b]
//   scan_block : 1 block, exclusive scan of bsum (nb <= 1024)
//   scan_final : block-local exclusive scan + bsum offset, in-place on cnt
// ---------------------------------------------------------------------------
__global__ __launch_bounds__(256)
void scan_reduce(const int* __restrict__ cnt, int* __restrict__ bsum, int N) {
    __shared__ int s[256];
    int t = threadIdx.x;
    int i = blockIdx.x * 256 + t;
    s[t] = (i < N) ? cnt[i] : 0;
    __syncthreads();
    for (int off = 128; off > 0; off >>= 1) {
        if (t < off) s[t] += s[t + off];
        __syncthreads();
    }
    if (t == 0) bsum[blockIdx.x] = s[0];
}

__global__ __launch_bounds__(1024)
void scan_block(int* __restrict__ bsum, int nb) {
    __shared__ int s[1024];
    int t = threadIdx.x;
    s[t] = (t < nb) ? bsum[t] : 0;
    __syncthreads();
    for (int off = 1; off < 1024; off <<= 1) {
        int o = (t >= off) ? s[t - off] : 0;
        __syncthreads();
        s[t] += o;
        __syncthreads();
    }
    if (t < nb) bsum[t] = (t == 0) ? 0 : s[t - 1];
}

__global__ __launch_bounds__(256)
void scan_final(int* __restrict__ cnt, const int* __restrict__ bsum, int N) {
    __shared__ int s[256];
    int t = threadIdx.x;
    int i = blockIdx.x * 256 + t;
    int v = (i < N) ? cnt[i] : 0;
    s[t] = v;
    __syncthreads();
    for (int off = 1; off < 256; off <<= 1) {
        int o = (t >= off) ? s[t - off] : 0;
        __syncthreads();
        s[t] += o;
        __syncthreads();
    }
    int ex = ((t == 0) ? 0 : s[t - 1]) + bsum[blockIdx.x];
    if (i < N) cnt[i] = ex;     // cnt becomes the segment-start cursor
}

// ---------------------------------------------------------------------------
// FUSED kernel: blocks [0, Tblocks) run the MFMA transform (independent of
// the sort), blocks [Tblocks, ...) run the counting-sort placement pass.
// Transform blocks are first so they start immediately; place blocks drain
// behind them — place's ~50us hides under the transform.
//
// Transform: H[r][n][i] = sum_j W[r][i][j]*nodes[n][j] (bf16 store), 128-node
// tile / 4 waves, LDS bf16 stride-136 (2-way-max bank aliasing = free).
// C/D layout: col = lane&15, row = quad*4 + reg. (verbatim from round 3)
// ---------------------------------------------------------------------------
__global__ __launch_bounds__(256, 2)
void fused_tp(const float* __restrict__ nodes,
              const float* __restrict__ weights,
              __hip_bfloat16* __restrict__ H,
              const int* __restrict__ rows, const int* __restrict__ cols,
              const float* __restrict__ vals,
              int* __restrict__ cursor, u64* __restrict__ sorted,
              int N, int R, int nnz, int Tblocks) {
    __shared__ unsigned short nd[128 * LDN];
    __shared__ unsigned short wt[128 * LDN];

    if ((int)blockIdx.x >= Tblocks) {
        // ---------------- place: counting-sort pass 2 ----------------
        int e = (blockIdx.x - Tblocks) * 256 + threadIdx.x;
        if (e >= nnz) return;
        int row = rows[e];
        int r   = row / N;
        int dst = row - r * N;
        int pos = atomicAdd(&cursor[dst], 1);
        unsigned int lo = (unsigned int)cols[e] | ((unsigned int)r << 17);
        u64 rec = ((u64)__float_as_uint(vals[e]) << 32) | (u64)lo;
        sorted[pos] = rec;
        return;
    }

    // ---------------- transform ----------------
    const int t    = threadIdx.x;
    const int n0   = blockIdx.x * 128;
    const int lane = t & 63;
    const int w    = t >> 6;
    const int m    = lane & 15;
    const int quad = lane >> 4;
    const int q8   = quad * 8;
    const int w32  = w * 32;

    const float4* src4 = reinterpret_cast<const float4*>(nodes);
#pragma unroll
    for (int it = 0; it < 8; ++it) {
        int id  = t + 256 * it;
        int row = id >> 4;
        int k8  = id & 15;
        float4 v0 = make_float4(0.f, 0.f, 0.f, 0.f);
        float4 v1 = v0;
        if (n0 + row < N) {
            v0 = src4[(size_t)(n0 + row) * 32 + k8 * 2];
            v1 = src4[(size_t)(n0 + row) * 32 + k8 * 2 + 1];
        }
        short8 sv;
        sv[0] = f2bf(v0.x); sv[1] = f2bf(v0.y); sv[2] = f2bf(v0.z); sv[3] = f2bf(v0.w);
        sv[4] = f2bf(v1.x); sv[5] = f2bf(v1.y); sv[6] = f2bf(v1.z); sv[7] = f2bf(v1.w);
        *reinterpret_cast<short8*>(&nd[row * LDN + k8 * 8]) = sv;
    }

    for (int r = 0; r < R; ++r) {
        __syncthreads();
        const float4* wsrc = reinterpret_cast<const float4*>(weights + (size_t)r * HFR * HTO);
#pragma unroll
        for (int it = 0; it < 8; ++it) {
            int id  = t + 256 * it;
            int row = id >> 4;
            int k8  = id & 15;
            float4 v0 = wsrc[row * 32 + k8 * 2];
            float4 v1 = wsrc[row * 32 + k8 * 2 + 1];
            short8 sv;
            sv[0] = f2bf(v0.x); sv[1] = f2bf(v0.y); sv[2] = f2bf(v0.z); sv[3] = f2bf(v0.w);
            sv[4] = f2bf(v1.x); sv[5] = f2bf(v1.y); sv[6] = f2bf(v1.z); sv[7] = f2bf(v1.w);
            *reinterpret_cast<short8*>(&wt[row * LDN + k8 * 8]) = sv;
        }
        __syncthreads();

        f32x4 acc[2][8];
#pragma unroll
        for (int t2 = 0; t2 < 2; ++t2)
#pragma unroll
            for (int j = 0; j < 8; ++j) acc[t2][j] = (f32x4)(0.f);

#pragma unroll
        for (int kk = 0; kk < HFR; kk += 32) {
            short8 a0 = *reinterpret_cast<const short8*>(&nd[(w32 +      m) * LDN + kk + q8]);
            short8 a1 = *reinterpret_cast<const short8*>(&nd[(w32 + 16 + m) * LDN + kk + q8]);
#pragma unroll
            for (int j = 0; j < 8; ++j) {
                short8 b = *reinterpret_cast<const short8*>(&wt[(j * 16 + m) * LDN + kk + q8]);
                acc[0][j] = __builtin_amdgcn_mfma_f32_16x16x32_bf16(a0, b, acc[0][j], 0, 0, 0);
                acc[1][j] = __builtin_amdgcn_mfma_f32_16x16x32_bf16(a1, b, acc[1][j], 0, 0, 0);
            }
        }

#pragma unroll
        for (int t2 = 0; t2 < 2; ++t2) {
            int rowbase = n0 + w32 + t2 * 16 + quad * 4;
#pragma unroll
            for (int reg = 0; reg < 4; ++reg) {
                int n = rowbase + reg;
                if (n < N) {
                    __hip_bfloat16* dst = H + ((size_t)r * N + n) * HTO + m;
#pragma unroll
                    for (int j = 0; j < 8; ++j)
                        dst[j * 16] = __float2bfloat16(acc[t2][j][reg]);
                }
            }
        }
    }
}

// ---------------------------------------------------------------------------
// pull-gather, unrolled x8: batch 8 record loads (scalar-cache eligible via
// readfirstlane), then 8 independent H-row loads in flight, 4 acc pairs.
// One wave per dst node; lane l owns features {2l, 2l+1}. No atomics.
// ---------------------------------------------------------------------------
__global__ __launch_bounds__(256)
void gather_kernel(const u64* __restrict__ sorted,
                   const int* __restrict__ cursor,
                   const __hip_bfloat16* __restrict__ H,
                   float* __restrict__ out, int N) {
    const int wave = threadIdx.x >> 6;
    const int lane = threadIdx.x & 63;
    const int n = blockIdx.x * 4 + wave;
    if (n >= N) return;

    int e         = (n == 0) ? 0 : cursor[n - 1];
    const int end = cursor[n];

    float a0 = 0.f, a1 = 0.f, b0 = 0.f, b1 = 0.f;
    float c0 = 0.f, c1 = 0.f, d0 = 0.f, d1 = 0.f;

    const unsigned short* Hu = reinterpret_cast<const unsigned short*>(H);

#define HROW(q) reinterpret_cast<const unsigned int*>( \
        Hu + ((((size_t)((unsigned int)(q) >> 17) & 7) * (size_t)N + \
               ((unsigned int)(q) & 0x1FFFF)) << 7))
#define VAL(q)  __uint_as_float((unsigned int)((q) >> 32))

    for (; e + 8 <= end; e += 8) {
        const u64* p = sorted + __builtin_amdgcn_readfirstlane(e);
        u64 q0 = p[0], q1 = p[1], q2 = p[2], q3 = p[3];
        u64 q4 = p[4], q5 = p[5], q6 = p[6], q7 = p[7];
        unsigned int x0 = HROW(q0)[lane];
        unsigned int x1 = HROW(q1)[lane];
        unsigned int x2 = HROW(q2)[lane];
        unsigned int x3 = HROW(q3)[lane];
        unsigned int x4 = HROW(q4)[lane];
        unsigned int x5 = HROW(q5)[lane];
        unsigned int x6 = HROW(q6)[lane];
        unsigned int x7 = HROW(q7)[lane];
        a0 = fmaf(bflo(x0), VAL(q0), a0); a1 = fmaf(bfhi(x0), VAL(q0), a1);
        b0 = fmaf(bflo(x1), VAL(q1), b0); b1 = fmaf(bfhi(x1), VAL(q1), b1);
        c0 = fmaf(bflo(x2), VAL(q2), c0); c1 = fmaf(bfhi(x2), VAL(q2), c1);
        d0 = fmaf(bflo(x3), VAL(q3), d0); d1 = fmaf(bfhi(x3), VAL(q3), d1);
        a0 = fmaf(bflo(x4), VAL(q4), a0); a1 = fmaf(bfhi(x4), VAL(q4), a1);
        b0 = fmaf(bflo(x5), VAL(q5), b0); b1 = fmaf(bfhi(x5), VAL(q5), b1);
        c0 = fmaf(bflo(x6), VAL(q6), c0); c1 = fmaf(bfhi(x6), VAL(q6), c1);
        d0 = fmaf(bflo(x7), VAL(q7), d0); d1 = fmaf(bfhi(x7), VAL(q7), d1);
    }
    for (; e + 2 <= end; e += 2) {
        const u64* p = sorted + __builtin_amdgcn_readfirstlane(e);
        u64 q0 = p[0], q1 = p[1];
        unsigned int x0 = HROW(q0)[lane];
        unsigned int x1 = HROW(q1)[lane];
        a0 = fmaf(bflo(x0), VAL(q0), a0); a1 = fmaf(bfhi(x0), VAL(q0), a1);
        b0 = fmaf(bflo(x1), VAL(q1), b0); b1 = fmaf(bfhi(x1), VAL(q1), b1);
    }
    if (e < end) {
        u64 q0 = sorted[e];
        unsigned int x0 = HROW(q0)[lane];
        a0 = fmaf(bflo(x0), VAL(q0), a0); a1 = fmaf(bfhi(x0), VAL(q0), a1);
    }
#undef HROW
#undef VAL

    float2 o;
    o.x = fmaxf(a0 + b0 + c0 + d0, 0.f);
    o.y = fmaxf(a1 + b1 + c1 + d1, 0.f);
    *reinterpret_cast<float2*>(out + (size_t)n * HTO + lane * 2) = o;
}

// ---------------------------------------------------------------------------
extern "C" void kernel_launch(void* const* d_in, const int* in_sizes, int n_in,
                              void* d_out, int out_size, void* d_ws, size_t ws_size,
                              hipStream_t stream) {
    const float* nodes   = (const float*)d_in[0];   // [N, HFR] fp32
    const int*   indices = (const int*)d_in[1];     // [2, NNZ] int32
    const float* vals    = (const float*)d_in[2];   // [NNZ] fp32
    const float* weights = (const float*)d_in[3];   // [R, HFR, HTO] fp32

    const int N   = in_sizes[0] / HFR;
    const int nnz = in_sizes[1] / 2;
    const int R   = in_sizes[3] / (HFR * HTO);

    const int* rows = indices;
    const int* cols = indices + nnz;

    // Workspace layout (same as round 3 + 4KB bsum):
    //   H      : [R, N, HTO] bf16   (204.8 MB)
    //   sorted : [nnz] u64          (12.8 MB)
    //   cnt    : [N] int            (0.4 MB)   histogram -> cursor -> seg-ends
    //   bsum   : [1024] int         (4 KB)
    char* ws = (char*)d_ws;
    __hip_bfloat16* H = (__hip_bfloat16*)ws;
    size_t off = (size_t)R * N * HTO * sizeof(__hip_bfloat16);
    u64* sorted = (u64*)(ws + off);
    off += (size_t)nnz * sizeof(u64);
    int* cnt = (int*)(ws + off);
    off += (size_t)N * sizeof(int);
    int* bsum = (int*)(ws + off);

    float* out = (float*)d_out;

    const int NB = (N + 255) / 256;        // 391 scan blocks (<= 1024)
    const int Tblocks = (N + 127) / 128;   // transform tiles
    const int Pblocks = (nnz + 255) / 256; // place blocks

    // 1) zero histogram
    zero_i32<<<NB, 256, 0, stream>>>(cnt, N);
    // 2) degree histogram
    count_kernel<<<Pblocks, 256, 0, stream>>>(rows, cnt, N, nnz);
    // 3) exclusive scan (hierarchical, coalesced)
    scan_reduce<<<NB, 256, 0, stream>>>(cnt, bsum, N);
    scan_block<<<1, 1024, 0, stream>>>(bsum, NB);
    scan_final<<<NB, 256, 0, stream>>>(cnt, bsum, N);
    // 4) transform (MFMA) in parallel with counting-sort placement
    fused_tp<<<Tblocks + Pblocks, 256, 0, stream>>>(nodes, weights, H,
                                                    rows, cols, vals,
                                                    cnt, sorted, N, R, nnz, Tblocks);
    // 5) pull-gather + relu
    gather_kernel<<<(N + 3) / 4, 256, 0, stream>>>(sorted, cnt, H, out, N);
}